// Round 7
// baseline (151.923 us; speedup 1.0000x reference)
//
#include <hip/hip_runtime.h>

// COLMAP reprojection residual.
// R4: pose-in-LDS 167->105. R6: fp16 point table (L2-fit) 105->90, FETCH
// 318->100MB. R7: test concurrency model — pack pose LDS to 40KB (fp16),
// block=512, launch_bounds(512,8) -> 4 blocks/CU = 32 waves/CU *with*
// UNROLL=4 per-wave MLP. If latency-capacity is code-limited (model A),
// expect ~60us; if HW MSHR-saturated (model B), flat ~90us => roofline.

typedef float    f2_t __attribute__((ext_vector_type(2)));
typedef _Float16 h4_t __attribute__((ext_vector_type(4)));
typedef _Float16 h2_t __attribute__((ext_vector_type(2)));

#define NCAM_MAX 2048   // 5 arrays * 2048 * 4B = 40 KB static LDS
#define UNROLL 4

__global__ __launch_bounds__(256) void prep_pts_h(
    const float* __restrict__ pts3, h4_t* __restrict__ ptsh, int n)
{
    int i = blockIdx.x * blockDim.x + threadIdx.x;
    if (i >= n) return;
    const float* p = pts3 + (long)i * 3;
    h4_t h;
    h.x = (_Float16)p[0];
    h.y = (_Float16)p[1];
    h.z = (_Float16)p[2];
    h.w = (_Float16)0.0f;
    ptsh[i] = h;
}

__device__ __forceinline__ void compute_one(
    float px, float py, float pz,
    float qx, float qy, float qz,
    float tx, float ty, float tz,
    float fl, unsigned kk,
    f2_t o, f2_t* r)
{
    float qw = sqrtf(fmaxf(0.0f, 1.0f - (qx*qx + qy*qy + qz*qz)));
    float ux = qy*pz - qz*py;
    float uy = qz*px - qx*pz;
    float uz = qx*py - qy*px;
    float wx = ux + qw*px;
    float wy = uy + qw*py;
    float wz = uz + qw*pz;
    float cx = qy*wz - qz*wy;
    float cy = qz*wx - qx*wz;
    float cz = qx*wy - qy*wx;
    float Px = px + 2.0f*cx + tx;
    float Py = py + 2.0f*cy + ty;
    float Pz = pz + 2.0f*cz + tz;
    float invz = 1.0f / Pz;
    float u = Px * invz;
    float v = Py * invz;
    float k1 = __uint_as_float(kk << 16);
    float k2 = __uint_as_float(kk & 0xffff0000u);
    float n = u*u + v*v;
    float d = 1.0f + k1*n + k2*n*n;
    float s = d * fl;
    r->x = u*s - o.x;
    r->y = v*s - o.y;
}

__global__ __launch_bounds__(512, 8) void reproj6_kernel(
    const float* __restrict__ p2d,
    const int* __restrict__ cidx,
    const int* __restrict__ pidx,
    const float* __restrict__ pose,
    const h4_t* __restrict__ ptsh,
    float* __restrict__ out,
    int M, int n_imgs)
{
    __shared__ h2_t s_txy[NCAM_MAX];   // {tx, ty} fp16
    __shared__ h2_t s_tzf[NCAM_MAX];   // {tz, f}  fp16
    __shared__ h2_t s_qxy[NCAM_MAX];   // {qx, qy} fp16
    __shared__ h2_t s_qz_[NCAM_MAX];   // {qz, 0}  fp16
    __shared__ unsigned s_kk[NCAM_MAX]; // {k1, k2} bf16-pair

    for (int r = threadIdx.x; r < n_imgs; r += blockDim.x) {
        const float* c = pose + (long)r * 10;
        float tx = c[0], ty = c[1], tz = c[2];
        float qx = c[3], qy = c[4], qz = c[5], qw = c[6];
        float fl = c[7], k1 = c[8], k2 = c[9];
        float inv = rsqrtf(qx*qx + qy*qy + qz*qz + qw*qw);
        if (qw < 0.0f) inv = -inv;
        qx *= inv; qy *= inv; qz *= inv;
        h2_t a; a.x = (_Float16)tx; a.y = (_Float16)ty; s_txy[r] = a;
        h2_t b; b.x = (_Float16)tz; b.y = (_Float16)fl; s_tzf[r] = b;
        h2_t d; d.x = (_Float16)qx; d.y = (_Float16)qy; s_qxy[r] = d;
        h2_t e; e.x = (_Float16)qz; e.y = (_Float16)0.0f; s_qz_[r] = e;
        unsigned b1 = (__float_as_uint(k1) + 0x8000u) >> 16;
        unsigned b2 = (__float_as_uint(k2) + 0x8000u) >> 16;
        s_kk[r] = (b1 & 0xffffu) | ((b2 & 0xffffu) << 16);
    }
    __syncthreads();

    int tid = blockIdx.x * blockDim.x + threadIdx.x;
    int stride = gridDim.x * blockDim.x;
    long step = (long)stride * UNROLL;

    for (long base = tid; base < M; base += step) {
        if (base + (long)(UNROLL - 1) * stride < M) {
            int ci[UNROLL], pi[UNROLL];
            #pragma unroll
            for (int k = 0; k < UNROLL; k++) {
                long i = base + (long)k * stride;
                ci[k] = __builtin_nontemporal_load(cidx + i);
                pi[k] = __builtin_nontemporal_load(pidx + i);
            }
            h4_t p[UNROLL];
            f2_t o[UNROLL];
            #pragma unroll
            for (int k = 0; k < UNROLL; k++) {
                p[k] = ptsh[pi[k]];    // 8B L2-resident gather
                o[k] = __builtin_nontemporal_load((const f2_t*)p2d + (base + (long)k * stride));
            }
            #pragma unroll
            for (int k = 0; k < UNROLL; k++) {
                int c = ci[k];
                h2_t txy = s_txy[c], tzf = s_tzf[c], qxy = s_qxy[c], qz_ = s_qz_[c];
                f2_t r;
                compute_one((float)p[k].x, (float)p[k].y, (float)p[k].z,
                            (float)qxy.x, (float)qxy.y, (float)qz_.x,
                            (float)txy.x, (float)txy.y, (float)tzf.x,
                            (float)tzf.y, s_kk[c], o[k], &r);
                __builtin_nontemporal_store(r, (f2_t*)out + (base + (long)k * stride));
            }
        } else {
            for (int k = 0; k < UNROLL; k++) {
                long i = base + (long)k * stride;
                if (i >= M) break;
                int c = __builtin_nontemporal_load(cidx + i);
                int pi1 = __builtin_nontemporal_load(pidx + i);
                h4_t p = ptsh[pi1];
                f2_t o = __builtin_nontemporal_load((const f2_t*)p2d + i);
                h2_t txy = s_txy[c], tzf = s_tzf[c], qxy = s_qxy[c], qz_ = s_qz_[c];
                f2_t r;
                compute_one((float)p.x, (float)p.y, (float)p.z,
                            (float)qxy.x, (float)qxy.y, (float)qz_.x,
                            (float)txy.x, (float)txy.y, (float)tzf.x,
                            (float)tzf.y, s_kk[c], o, &r);
                __builtin_nontemporal_store(r, (f2_t*)out + i);
            }
        }
    }
}

// Fallback: direct per-obs kernel (ws too small or too many cameras).
__global__ __launch_bounds__(256) void reproj_direct_kernel(
    const float2* __restrict__ p2d,
    const int* __restrict__ cidx,
    const int* __restrict__ pidx,
    const float* __restrict__ pose,
    const float* __restrict__ pts3,
    float2* __restrict__ out,
    int M)
{
    int i = blockIdx.x * blockDim.x + threadIdx.x;
    if (i >= M) return;
    int ci = cidx[i];
    int pi = pidx[i];
    const float* cam = pose + (long)ci * 10;
    float tx = cam[0], ty = cam[1], tz = cam[2];
    float qx = cam[3], qy = cam[4], qz = cam[5], qw = cam[6];
    float f  = cam[7], k1 = cam[8], k2 = cam[9];
    float inv = rsqrtf(qx*qx + qy*qy + qz*qz + qw*qw);
    qx *= inv; qy *= inv; qz *= inv; qw *= inv;
    const float* pp = pts3 + (long)pi * 3;
    float px = pp[0], py = pp[1], pz = pp[2];
    float ux = qy*pz - qz*py;
    float uy = qz*px - qx*pz;
    float uz = qx*py - qy*px;
    float wx = ux + qw*px;
    float wy = uy + qw*py;
    float wz = uz + qw*pz;
    float cx = qy*wz - qz*wy;
    float cy = qz*wx - qx*wz;
    float cz = qx*wy - qy*wx;
    float Px = px + 2.0f*cx + tx;
    float Py = py + 2.0f*cy + ty;
    float Pz = pz + 2.0f*cz + tz;
    float invz = 1.0f / Pz;
    float u = Px * invz;
    float v = Py * invz;
    float n = u*u + v*v;
    float d = 1.0f + k1*n + k2*n*n;
    float s = d * f;
    float2 o = p2d[i];
    out[i] = make_float2(u*s - o.x, v*s - o.y);
}

extern "C" void kernel_launch(void* const* d_in, const int* in_sizes, int n_in,
                              void* d_out, int out_size, void* d_ws, size_t ws_size,
                              hipStream_t stream) {
    const float* p2d  = (const float*)d_in[0];
    const int*   cidx = (const int*)d_in[1];
    const int*   pidx = (const int*)d_in[2];
    const float* pose = (const float*)d_in[3];
    const float* pts3 = (const float*)d_in[4];

    int M      = in_sizes[1];
    int n_imgs = in_sizes[3] / 10;
    int n_pts  = in_sizes[4] / 3;

    size_t need = (size_t)n_pts * 8;

    if (ws_size >= need && n_imgs <= NCAM_MAX) {
        h4_t* ptsh = (h4_t*)d_ws;
        prep_pts_h<<<(n_pts + 255) / 256, 256, 0, stream>>>(pts3, ptsh, n_pts);
        int block = 512;
        int grid  = 1024;   // 4 blocks/CU (40KB LDS each) = 32 waves/CU
        reproj6_kernel<<<grid, block, 0, stream>>>(
            p2d, cidx, pidx, pose, ptsh, (float*)d_out, M, n_imgs);
    } else {
        reproj_direct_kernel<<<(M + 255) / 256, 256, 0, stream>>>(
            (const float2*)p2d, cidx, pidx, pose, pts3, (float2*)d_out, M);
    }
}

// Round 8
// 116.675 us; speedup vs baseline: 1.3021x; 1.3021x over previous
//
#include <hip/hip_runtime.h>

// COLMAP reprojection residual.
// History: R4 pose-in-LDS 167->105us. R6 fp16 point table (L2-fit) ->90us,
// FETCH 318->100MB. R7 FAILED: launch_bounds(512,8) reg-cap (VGPR 32) caused
// spill/serialization, 151us, FETCH 313MB. Lesson: never cap VGPR below the
// unroll's needs.
// R8: discriminate concurrency model properly. R6 structure (block=1024,
// fp32 pose LDS, fp16 table, compiler-chosen VGPR<=128) + UNROLL=8 +
// consecutive-per-thread streams (int4/float4 NT). In-flight gathers/CU
// ~2-3x R6. Model A (code-limited) -> ~60-70us; Model B (MSHR cap) -> flat.

typedef float    f2_t __attribute__((ext_vector_type(2)));
typedef float    f4_t __attribute__((ext_vector_type(4)));
typedef int      i4_t __attribute__((ext_vector_type(4)));
typedef _Float16 h4_t __attribute__((ext_vector_type(4)));

#define NCAM_MAX 2032   // 8 arrays * 2032 * 4B = 63.5 KB static LDS
#define UNROLL 8        // obs per thread, consecutive

__global__ __launch_bounds__(256) void prep_pts_h(
    const float* __restrict__ pts3, h4_t* __restrict__ ptsh, int n)
{
    int i = blockIdx.x * blockDim.x + threadIdx.x;
    if (i >= n) return;
    const float* p = pts3 + (long)i * 3;
    h4_t h;
    h.x = (_Float16)p[0];
    h.y = (_Float16)p[1];
    h.z = (_Float16)p[2];
    h.w = (_Float16)0.0f;
    ptsh[i] = h;
}

__device__ __forceinline__ void compute_one(
    float px, float py, float pz,
    float qx, float qy, float qz,
    float tx, float ty, float tz,
    float fl, unsigned kk,
    float ox, float oy, float* rx, float* ry)
{
    float qw = sqrtf(fmaxf(0.0f, 1.0f - (qx*qx + qy*qy + qz*qz)));
    float ux = qy*pz - qz*py;
    float uy = qz*px - qx*pz;
    float uz = qx*py - qy*px;
    float wx = ux + qw*px;
    float wy = uy + qw*py;
    float wz = uz + qw*pz;
    float cx = qy*wz - qz*wy;
    float cy = qz*wx - qx*wz;
    float cz = qx*wy - qy*wx;
    float Px = px + 2.0f*cx + tx;
    float Py = py + 2.0f*cy + ty;
    float Pz = pz + 2.0f*cz + tz;
    float invz = 1.0f / Pz;
    float u = Px * invz;
    float v = Py * invz;
    float k1 = __uint_as_float(kk << 16);
    float k2 = __uint_as_float(kk & 0xffff0000u);
    float n = u*u + v*v;
    float d = 1.0f + k1*n + k2*n*n;
    float s = d * fl;
    *rx = u*s - ox;
    *ry = v*s - oy;
}

__global__ __launch_bounds__(1024) void reproj8_kernel(
    const float* __restrict__ p2d,
    const int* __restrict__ cidx,
    const int* __restrict__ pidx,
    const float* __restrict__ pose,
    const h4_t* __restrict__ ptsh,
    float* __restrict__ out,
    int M, int n_imgs)
{
    __shared__ float s_tx[NCAM_MAX], s_ty[NCAM_MAX], s_tz[NCAM_MAX];
    __shared__ float s_qx[NCAM_MAX], s_qy[NCAM_MAX], s_qz[NCAM_MAX];
    __shared__ float s_fl[NCAM_MAX];
    __shared__ unsigned s_kk[NCAM_MAX];

    for (int r = threadIdx.x; r < n_imgs; r += blockDim.x) {
        const float* c = pose + (long)r * 10;
        float tx = c[0], ty = c[1], tz = c[2];
        float qx = c[3], qy = c[4], qz = c[5], qw = c[6];
        float fl = c[7], k1 = c[8], k2 = c[9];
        float inv = rsqrtf(qx*qx + qy*qy + qz*qz + qw*qw);
        if (qw < 0.0f) inv = -inv;
        qx *= inv; qy *= inv; qz *= inv;
        s_tx[r] = tx; s_ty[r] = ty; s_tz[r] = tz;
        s_qx[r] = qx; s_qy[r] = qy; s_qz[r] = qz;
        s_fl[r] = fl;
        unsigned b1 = (__float_as_uint(k1) + 0x8000u) >> 16;
        unsigned b2 = (__float_as_uint(k2) + 0x8000u) >> 16;
        s_kk[r] = (b1 & 0xffffu) | ((b2 & 0xffffu) << 16);
    }
    __syncthreads();

    long T = (long)blockIdx.x * blockDim.x + threadIdx.x;
    long base = T * UNROLL;

    if (base + UNROLL <= M) {
        // --- fast path: 8 consecutive obs per thread, vectorized streams ---
        i4_t c01 = __builtin_nontemporal_load((const i4_t*)(cidx + base));
        i4_t c23 = __builtin_nontemporal_load((const i4_t*)(cidx + base) + 1);
        i4_t q01 = __builtin_nontemporal_load((const i4_t*)(pidx + base));
        i4_t q23 = __builtin_nontemporal_load((const i4_t*)(pidx + base) + 1);
        int ci[UNROLL] = {c01.x, c01.y, c01.z, c01.w, c23.x, c23.y, c23.z, c23.w};
        int pi[UNROLL] = {q01.x, q01.y, q01.z, q01.w, q23.x, q23.y, q23.z, q23.w};

        h4_t p[UNROLL];
        #pragma unroll
        for (int k = 0; k < UNROLL; k++) p[k] = ptsh[pi[k]];  // 8 independent L2 gathers

        f4_t o[UNROLL/2];
        #pragma unroll
        for (int k = 0; k < UNROLL/2; k++)
            o[k] = __builtin_nontemporal_load((const f4_t*)(p2d + 2*base) + k);

        f4_t r[UNROLL/2];
        #pragma unroll
        for (int k = 0; k < UNROLL; k++) {
            int c = ci[k];
            float ox = (k & 1) ? o[k>>1].z : o[k>>1].x;
            float oy = (k & 1) ? o[k>>1].w : o[k>>1].y;
            float rx, ry;
            compute_one((float)p[k].x, (float)p[k].y, (float)p[k].z,
                        s_qx[c], s_qy[c], s_qz[c],
                        s_tx[c], s_ty[c], s_tz[c],
                        s_fl[c], s_kk[c], ox, oy, &rx, &ry);
            if (k & 1) { r[k>>1].z = rx; r[k>>1].w = ry; }
            else       { r[k>>1].x = rx; r[k>>1].y = ry; }
        }
        #pragma unroll
        for (int k = 0; k < UNROLL/2; k++)
            __builtin_nontemporal_store(r[k], (f4_t*)(out + 2*base) + k);
    } else {
        // --- tail: per-element guard ---
        for (int k = 0; k < UNROLL; k++) {
            long i = base + k;
            if (i >= M) break;
            int c = cidx[i];
            int pi1 = pidx[i];
            h4_t p = ptsh[pi1];
            f2_t o = __builtin_nontemporal_load((const f2_t*)p2d + i);
            float rx, ry;
            compute_one((float)p.x, (float)p.y, (float)p.z,
                        s_qx[c], s_qy[c], s_qz[c],
                        s_tx[c], s_ty[c], s_tz[c],
                        s_fl[c], s_kk[c], o.x, o.y, &rx, &ry);
            f2_t r; r.x = rx; r.y = ry;
            __builtin_nontemporal_store(r, (f2_t*)out + i);
        }
    }
}

// Fallback: direct per-obs kernel (ws too small or too many cameras).
__global__ __launch_bounds__(256) void reproj_direct_kernel(
    const float2* __restrict__ p2d,
    const int* __restrict__ cidx,
    const int* __restrict__ pidx,
    const float* __restrict__ pose,
    const float* __restrict__ pts3,
    float2* __restrict__ out,
    int M)
{
    int i = blockIdx.x * blockDim.x + threadIdx.x;
    if (i >= M) return;
    int ci = cidx[i];
    int pi = pidx[i];
    const float* cam = pose + (long)ci * 10;
    float tx = cam[0], ty = cam[1], tz = cam[2];
    float qx = cam[3], qy = cam[4], qz = cam[5], qw = cam[6];
    float f  = cam[7], k1 = cam[8], k2 = cam[9];
    float inv = rsqrtf(qx*qx + qy*qy + qz*qz + qw*qw);
    qx *= inv; qy *= inv; qz *= inv; qw *= inv;
    const float* pp = pts3 + (long)pi * 3;
    float px = pp[0], py = pp[1], pz = pp[2];
    float ux = qy*pz - qz*py;
    float uy = qz*px - qx*pz;
    float uz = qx*py - qy*px;
    float wx = ux + qw*px;
    float wy = uy + qw*py;
    float wz = uz + qw*pz;
    float cx = qy*wz - qz*wy;
    float cy = qz*wx - qx*wz;
    float cz = qx*wy - qy*wx;
    float Px = px + 2.0f*cx + tx;
    float Py = py + 2.0f*cy + ty;
    float Pz = pz + 2.0f*cz + tz;
    float invz = 1.0f / Pz;
    float u = Px * invz;
    float v = Py * invz;
    float n = u*u + v*v;
    float d = 1.0f + k1*n + k2*n*n;
    float s = d * f;
    float2 o = p2d[i];
    out[i] = make_float2(u*s - o.x, v*s - o.y);
}

extern "C" void kernel_launch(void* const* d_in, const int* in_sizes, int n_in,
                              void* d_out, int out_size, void* d_ws, size_t ws_size,
                              hipStream_t stream) {
    const float* p2d  = (const float*)d_in[0];
    const int*   cidx = (const int*)d_in[1];
    const int*   pidx = (const int*)d_in[2];
    const float* pose = (const float*)d_in[3];
    const float* pts3 = (const float*)d_in[4];

    int M      = in_sizes[1];
    int n_imgs = in_sizes[3] / 10;
    int n_pts  = in_sizes[4] / 3;

    size_t need = (size_t)n_pts * 8;

    if (ws_size >= need && n_imgs <= NCAM_MAX) {
        h4_t* ptsh = (h4_t*)d_ws;
        prep_pts_h<<<(n_pts + 255) / 256, 256, 0, stream>>>(pts3, ptsh, n_pts);
        int block = 1024;
        long threads_needed = ((long)M + UNROLL - 1) / UNROLL;
        int grid = (int)((threads_needed + block - 1) / block);
        reproj8_kernel<<<grid, block, 0, stream>>>(
            p2d, cidx, pidx, pose, ptsh, (float*)d_out, M, n_imgs);
    } else {
        reproj_direct_kernel<<<(M + 255) / 256, 256, 0, stream>>>(
            (const float2*)p2d, cidx, pidx, pose, pts3, (float2*)d_out, M);
    }
}

// Round 9
// 99.100 us; speedup vs baseline: 1.5330x; 1.1773x over previous
//
#include <hip/hip_runtime.h>

// COLMAP reprojection residual.
// History: R4 pose-in-LDS 167->105us. R6 fp16 point table (L2-fit) 105->90us
// (FETCH 318->100MB). R5/R8: code-side MLP x4/x8 NULL => per-CU miss-queue
// (~48-64 lines in flight) is saturated; only per-line LATENCY moves time.
// R9 probe: gather via agent-scope load (bypasses L1, served by L2 directly).
// If the L1-bypass path queues deeper -> ~60-75us; if flat ~90us, the cap is
// path-independent => structural roofline for random 8B gathers.
// Structure otherwise identical to R6 (best): block=1024 grid=512, strided
// UNROLL=4, fp32 pose LDS (63.5KB), fp16 8B point records, NT f2 streams.

typedef float    f2_t __attribute__((ext_vector_type(2)));
typedef _Float16 h4_t __attribute__((ext_vector_type(4)));

#define NCAM_MAX 2032   // 8 arrays * 2032 * 4B = 63.5 KB static LDS
#define UNROLL 4

__global__ __launch_bounds__(256) void prep_pts_h(
    const float* __restrict__ pts3, h4_t* __restrict__ ptsh, int n)
{
    int i = blockIdx.x * blockDim.x + threadIdx.x;
    if (i >= n) return;
    const float* p = pts3 + (long)i * 3;
    h4_t h;
    h.x = (_Float16)p[0];
    h.y = (_Float16)p[1];
    h.z = (_Float16)p[2];
    h.w = (_Float16)0.0f;
    ptsh[i] = h;
}

__device__ __forceinline__ h4_t load_pt_bypass(const h4_t* ptsh, int pi)
{
    // Agent(device)-scope relaxed load: emits global_load_dwordx2 with
    // L1-bypass coherence bits; data served straight from L2. Bit-exact.
    unsigned long long raw = __hip_atomic_load(
        (const unsigned long long*)(ptsh + pi),
        __ATOMIC_RELAXED, __HIP_MEMORY_SCOPE_AGENT);
    union { unsigned long long u; h4_t h; } cvt;
    cvt.u = raw;
    return cvt.h;
}

__device__ __forceinline__ void compute_one(
    float px, float py, float pz,
    float qx, float qy, float qz,
    float tx, float ty, float tz,
    float fl, unsigned kk,
    f2_t o, f2_t* r)
{
    float qw = sqrtf(fmaxf(0.0f, 1.0f - (qx*qx + qy*qy + qz*qz)));
    float ux = qy*pz - qz*py;
    float uy = qz*px - qx*pz;
    float uz = qx*py - qy*px;
    float wx = ux + qw*px;
    float wy = uy + qw*py;
    float wz = uz + qw*pz;
    float cx = qy*wz - qz*wy;
    float cy = qz*wx - qx*wz;
    float cz = qx*wy - qy*wx;
    float Px = px + 2.0f*cx + tx;
    float Py = py + 2.0f*cy + ty;
    float Pz = pz + 2.0f*cz + tz;
    float invz = 1.0f / Pz;
    float u = Px * invz;
    float v = Py * invz;
    float k1 = __uint_as_float(kk << 16);
    float k2 = __uint_as_float(kk & 0xffff0000u);
    float n = u*u + v*v;
    float d = 1.0f + k1*n + k2*n*n;
    float s = d * fl;
    r->x = u*s - o.x;
    r->y = v*s - o.y;
}

__global__ __launch_bounds__(1024) void reproj9_kernel(
    const float* __restrict__ p2d,
    const int* __restrict__ cidx,
    const int* __restrict__ pidx,
    const float* __restrict__ pose,
    const h4_t* __restrict__ ptsh,
    float* __restrict__ out,
    int M, int n_imgs)
{
    __shared__ float s_tx[NCAM_MAX], s_ty[NCAM_MAX], s_tz[NCAM_MAX];
    __shared__ float s_qx[NCAM_MAX], s_qy[NCAM_MAX], s_qz[NCAM_MAX];
    __shared__ float s_fl[NCAM_MAX];
    __shared__ unsigned s_kk[NCAM_MAX];

    for (int r = threadIdx.x; r < n_imgs; r += blockDim.x) {
        const float* c = pose + (long)r * 10;
        float tx = c[0], ty = c[1], tz = c[2];
        float qx = c[3], qy = c[4], qz = c[5], qw = c[6];
        float fl = c[7], k1 = c[8], k2 = c[9];
        float inv = rsqrtf(qx*qx + qy*qy + qz*qz + qw*qw);
        if (qw < 0.0f) inv = -inv;
        qx *= inv; qy *= inv; qz *= inv;
        s_tx[r] = tx; s_ty[r] = ty; s_tz[r] = tz;
        s_qx[r] = qx; s_qy[r] = qy; s_qz[r] = qz;
        s_fl[r] = fl;
        unsigned b1 = (__float_as_uint(k1) + 0x8000u) >> 16;
        unsigned b2 = (__float_as_uint(k2) + 0x8000u) >> 16;
        s_kk[r] = (b1 & 0xffffu) | ((b2 & 0xffffu) << 16);
    }
    __syncthreads();

    int tid = blockIdx.x * blockDim.x + threadIdx.x;
    int stride = gridDim.x * blockDim.x;
    long step = (long)stride * UNROLL;

    for (long base = tid; base < M; base += step) {
        if (base + (long)(UNROLL - 1) * stride < M) {
            int ci[UNROLL], pi[UNROLL];
            #pragma unroll
            for (int k = 0; k < UNROLL; k++) {
                long i = base + (long)k * stride;
                ci[k] = __builtin_nontemporal_load(cidx + i);
                pi[k] = __builtin_nontemporal_load(pidx + i);
            }
            h4_t p[UNROLL];
            f2_t o[UNROLL];
            #pragma unroll
            for (int k = 0; k < UNROLL; k++) {
                p[k] = load_pt_bypass(ptsh, pi[k]);   // L1-bypass L2 gather
                o[k] = __builtin_nontemporal_load((const f2_t*)p2d + (base + (long)k * stride));
            }
            #pragma unroll
            for (int k = 0; k < UNROLL; k++) {
                int c = ci[k];
                f2_t r;
                compute_one((float)p[k].x, (float)p[k].y, (float)p[k].z,
                            s_qx[c], s_qy[c], s_qz[c],
                            s_tx[c], s_ty[c], s_tz[c],
                            s_fl[c], s_kk[c], o[k], &r);
                __builtin_nontemporal_store(r, (f2_t*)out + (base + (long)k * stride));
            }
        } else {
            for (int k = 0; k < UNROLL; k++) {
                long i = base + (long)k * stride;
                if (i >= M) break;
                int c = __builtin_nontemporal_load(cidx + i);
                int pi1 = __builtin_nontemporal_load(pidx + i);
                h4_t p = load_pt_bypass(ptsh, pi1);
                f2_t o = __builtin_nontemporal_load((const f2_t*)p2d + i);
                f2_t r;
                compute_one((float)p.x, (float)p.y, (float)p.z,
                            s_qx[c], s_qy[c], s_qz[c],
                            s_tx[c], s_ty[c], s_tz[c],
                            s_fl[c], s_kk[c], o, &r);
                __builtin_nontemporal_store(r, (f2_t*)out + i);
            }
        }
    }
}

// Fallback: direct per-obs kernel (ws too small or too many cameras).
__global__ __launch_bounds__(256) void reproj_direct_kernel(
    const float2* __restrict__ p2d,
    const int* __restrict__ cidx,
    const int* __restrict__ pidx,
    const float* __restrict__ pose,
    const float* __restrict__ pts3,
    float2* __restrict__ out,
    int M)
{
    int i = blockIdx.x * blockDim.x + threadIdx.x;
    if (i >= M) return;
    int ci = cidx[i];
    int pi = pidx[i];
    const float* cam = pose + (long)ci * 10;
    float tx = cam[0], ty = cam[1], tz = cam[2];
    float qx = cam[3], qy = cam[4], qz = cam[5], qw = cam[6];
    float f  = cam[7], k1 = cam[8], k2 = cam[9];
    float inv = rsqrtf(qx*qx + qy*qy + qz*qz + qw*qw);
    qx *= inv; qy *= inv; qz *= inv; qw *= inv;
    const float* pp = pts3 + (long)pi * 3;
    float px = pp[0], py = pp[1], pz = pp[2];
    float ux = qy*pz - qz*py;
    float uy = qz*px - qx*pz;
    float uz = qx*py - qy*px;
    float wx = ux + qw*px;
    float wy = uy + qw*py;
    float wz = uz + qw*pz;
    float cx = qy*wz - qz*wy;
    float cy = qz*wx - qx*wz;
    float cz = qx*wy - qy*wx;
    float Px = px + 2.0f*cx + tx;
    float Py = py + 2.0f*cy + ty;
    float Pz = pz + 2.0f*cz + tz;
    float invz = 1.0f / Pz;
    float u = Px * invz;
    float v = Py * invz;
    float n = u*u + v*v;
    float d = 1.0f + k1*n + k2*n*n;
    float s = d * f;
    float2 o = p2d[i];
    out[i] = make_float2(u*s - o.x, v*s - o.y);
}

extern "C" void kernel_launch(void* const* d_in, const int* in_sizes, int n_in,
                              void* d_out, int out_size, void* d_ws, size_t ws_size,
                              hipStream_t stream) {
    const float* p2d  = (const float*)d_in[0];
    const int*   cidx = (const int*)d_in[1];
    const int*   pidx = (const int*)d_in[2];
    const float* pose = (const float*)d_in[3];
    const float* pts3 = (const float*)d_in[4];

    int M      = in_sizes[1];
    int n_imgs = in_sizes[3] / 10;
    int n_pts  = in_sizes[4] / 3;

    size_t need = (size_t)n_pts * 8;

    if (ws_size >= need && n_imgs <= NCAM_MAX) {
        h4_t* ptsh = (h4_t*)d_ws;
        prep_pts_h<<<(n_pts + 255) / 256, 256, 0, stream>>>(pts3, ptsh, n_pts);
        int block = 1024;
        int grid  = 512;   // LDS-limited 2 blocks/CU, grid-stride
        reproj9_kernel<<<grid, block, 0, stream>>>(
            p2d, cidx, pidx, pose, ptsh, (float*)d_out, M, n_imgs);
    } else {
        reproj_direct_kernel<<<(M + 255) / 256, 256, 0, stream>>>(
            (const float2*)p2d, cidx, pidx, pose, pts3, (float2*)d_out, M);
    }
}